// Round 16
// baseline (4709.925 us; speedup 1.0000x reference)
//
#include <hip/hip_runtime.h>
#include <math.h>

#define NOT_FIREDf 9999.0f
typedef float f32x2 __attribute__((ext_vector_type(2)));

// packed f32x2 add (bit-exact element-wise IEEE add, 1 inst for 2 adds)
#define PKADD(ACC, W) asm("v_pk_add_f32 %0, %0, %1" : "+v"(ACC) : "v"(W))

// Paired-row conv2 table in d_ws (f32x2 elements):
// w2q[((ci*6 + dA)*19 + rx)*64 + co] = { wA, wB } where
//   wA = (dA<=4 && rx-7 in [0,5)) ? w2[(co*12+ci)*25 + dA*5     + rx-7] : 0   (row oyb,   dy=dA)
//   wB = (dA>=1 && rx-7 in [0,5)) ? w2[(co*12+ci)*25 + (dA-1)*5 + rx-7] : 0   (row oyb+1, dy=dA-1)
// 12*6*19*64 = 87552 f32x2 = 175104 floats = 700416 bytes.
__global__ void w2q_pad_kernel(const float* __restrict__ w2, float* __restrict__ w2q) {
    int idx = blockIdx.x * 256 + threadIdx.x;
    if (idx >= 175104) return;
    int half = idx & 1;
    int e = idx >> 1;            // f32x2 element index
    int co = e & 63;
    int r = e >> 6;              // ci*114 + dA*19 + rx
    int rx = r % 19;
    int q = r / 19;
    int dA = q % 6;
    int ci = q / 6;
    int dy = dA - half;
    int dx = rx - 7;
    float v = 0.0f;
    if ((unsigned)dy < 5u && (unsigned)dx < 5u)
        v = w2[(co * 12 + ci) * 25 + dy * 5 + dx];
    w2q[idx] = v;
}

// v1 gather: 6 pk-adds of one w1 row (12 ch) into reg pairs
#define GATHER_V1(S, Y, X) do {                                              \
    const int dy_ = py - (Y), dx_ = px - (X);                                \
    if (((unsigned)dy_ < 5u) & ((unsigned)dx_ < 5u)) {                       \
        const f32x2* wp_ = (const f32x2*)&w1s[(dy_ * 5 + dx_) * 12];         \
        PKADD(v1r[S][0], wp_[0]); PKADD(v1r[S][1], wp_[1]);                  \
        PKADD(v1r[S][2], wp_[2]); PKADD(v1r[S][3], wp_[3]);                  \
        PKADD(v1r[S][4], wp_[4]); PKADD(v1r[S][5], wp_[5]);                  \
    } } while (0)

#define P1EVENT(PK) do {                                                     \
    const int py = (int)((PK) >> 8);                                         \
    const int px = (int)((PK) & 255u);                                       \
    GATHER_V1(0, y0, x0);                                                    \
    GATHER_V1(1, y1, x1);                                                    \
    if (has2) GATHER_V1(2, y2, x2);                                          \
  } while (0)

// stepwise bias pk-add (biases read from LDS) + max-screen + rare exact pass
#define CHECK_V1G(S, Y, X) do {                                              \
    const f32x2* bp_ = (const f32x2*)b1s;                                    \
    PKADD(v1r[S][0], bp_[0]); PKADD(v1r[S][1], bp_[1]);                      \
    PKADD(v1r[S][2], bp_[2]); PKADD(v1r[S][3], bp_[3]);                      \
    PKADD(v1r[S][4], bp_[4]); PKADD(v1r[S][5], bp_[5]);                      \
    float m_ = fmaxf(fmaxf(fmaxf(v1r[S][0].x, v1r[S][0].y),                  \
                           fmaxf(v1r[S][1].x, v1r[S][1].y)),                 \
                     fmaxf(fmaxf(v1r[S][2].x, v1r[S][2].y),                  \
                           fmaxf(v1r[S][3].x, v1r[S][3].y)));                \
    m_ = fmaxf(m_, fmaxf(fmaxf(v1r[S][4].x, v1r[S][4].y),                    \
                         fmaxf(v1r[S][5].x, v1r[S][5].y)));                  \
    if (m_ >= th) {                                                          \
        _Pragma("unroll")                                                    \
        for (int jj = 0; jj < 6; ++jj) {                                     \
            _Pragma("unroll")                                                \
            for (int el = 0; el < 2; ++el) {                                 \
                const float v_ = el ? v1r[S][jj].y : v1r[S][jj].x;           \
                if (v_ >= th) {                                              \
                    if (el) v1r[S][jj].y = -__builtin_inff();                \
                    else    v1r[S][jj].x = -__builtin_inff();                \
                    const int c_ = jj * 2 + el;                              \
                    const int pyp_ = (Y) >> 1, pxp_ = (X) >> 1;              \
                    const int p_ = c_ * 144 + pyp_ * 12 + pxp_;              \
                    const unsigned bit_ = 1u << (p_ & 31);                   \
                    const unsigned old_ = atomicOr(&pm1[p_ >> 5], bit_);     \
                    if (!(old_ & bit_)) {                                    \
                        const int pos_ = atomicAdd(&cnt1[t], 1);             \
                        ev1b[t & 1][pos_] =                                  \
                            (unsigned short)((c_ << 8) | (pyp_ << 4) | pxp_);\
                    }                                                        \
                }                                                            \
            }                                                                \
        }                                                                    \
    } } while (0)

// one phase-2 event: 8 paired-row dwordx2 loads -> 8 pk-adds (two half-batches)
#define P2_ONE(PA) do {                                                      \
    const int dA_ = (((PA) >> 4) & 15) - oyb_s;                              \
    if ((unsigned)dA_ < 6u) {                                                \
        const int ci_ = (PA) >> 8;                                           \
        const int px_ = (PA) & 15;                                           \
        const f32x2* q_ = w2q + ((ci_ * 6 + dA_) * 19 + px_ + 7) * 64 + lane; \
        f32x2 la_[4];                                                        \
        _Pragma("unroll")                                                    \
        for (int j = 0; j < 4; ++j) la_[j] = q_[-(j * 64)];                  \
        _Pragma("unroll")                                                    \
        for (int j = 0; j < 4; ++j) PKADD(v2r2[j], la_[j]);                  \
        _Pragma("unroll")                                                    \
        for (int j = 0; j < 4; ++j) la_[j] = q_[-((4 + j) * 64)];            \
        _Pragma("unroll")                                                    \
        for (int j = 0; j < 4; ++j) PKADD(v2r2[4 + j], la_[j]);              \
    } } while (0)

template <int USE_T>
__global__ void __launch_bounds__(256, 4)
snn_sim_kernel(const float* __restrict__ img,
               const float* __restrict__ w1g,
               const float* __restrict__ b1g,
               const float* __restrict__ b2g,
               const float* __restrict__ w2raw,
               const f32x2* __restrict__ w2q,
               const float* __restrict__ fcw,
               const float* __restrict__ b3g,
               float* __restrict__ out) {
    const int bimg = blockIdx.x;
    const int tid  = threadIdx.x;
    const int lane = tid & 63;
    const int wv   = tid >> 6;   // 4 waves
    const int oyb_s = __builtin_amdgcn_readfirstlane(wv) * 2;   // wave-uniform SGPR

    __shared__ __align__(16) float w1s[300];   // transposed: [k=ky*5+kx][c]
    __shared__ __align__(8)  float b1s[12];
    __shared__ float th_lds[80];
    __shared__ unsigned char  stin[784];
    __shared__ unsigned short evlist[784];     // t-sorted schedule, packed (py<<8|px)
    __shared__ unsigned short off[81];
    __shared__ unsigned int   hist[80];
    __shared__ __align__(8) unsigned short ev1b[2][1728];  // pooled-l1 events, dbuf
    __shared__ int            cnt1[80];        // per-step counters, never reset
    __shared__ unsigned int   pm1[54];
    __shared__ unsigned int   pm2[32];
    __shared__ unsigned int   e2list[1024];    // persistent: (t<<16) | nhwc_flat_idx
    __shared__ int            e2_cnt;

    // ---- init ----
    for (int i = tid; i < 300; i += 256) {
        int k = i / 12, c = i - k * 12;
        w1s[i] = w1g[c * 25 + k];
    }
    if (tid < 12) b1s[tid] = b1g[tid];
    if (tid < 80) {
        float xa = (0.0f - (float)tid) / 20.0f;
        th_lds[tid] = (float)exp((double)xa);            // correctly-rounded f32 exp
        hist[tid] = 0u;
        cnt1[tid] = 0;
    }
    if (tid < 54) pm1[tid] = 0u;
    if (tid < 32) pm2[tid] = 0u;
    if (tid == 0) e2_cnt = 0;
    for (int i = tid; i < 784; i += 256) {
        float p = img[bimg * 784 + i];
        p = fmaxf(p, 1e-5f);
        float lg = (float)log((double)p);                // correctly-rounded f32 log
        float s = ceilf(fmaxf(-17.452274f * lg, 0.0f));
        stin[i] = (unsigned char)(int)fminf(s, 255.0f);
    }
    __syncthreads();
    for (int i = tid; i < 784; i += 256) {
        int t = stin[i];
        if (t < 80) atomicAdd(&hist[t], 1u);
    }
    __syncthreads();
    if (tid == 0) {
        unsigned int acc = 0;
        for (int t = 0; t < 80; ++t) { off[t] = (unsigned short)acc; acc += hist[t]; }
        off[80] = (unsigned short)acc;
    }
    __syncthreads();
    if (tid < 80) {                            // deterministic pixel-order fill per t-bin
        int k = off[tid];
        for (int i = 0; i < 784; ++i)
            if ((int)stin[i] == tid) {
                int py = i / 28;
                evlist[k++] = (unsigned short)((py << 8) | (i - py * 28));
            }
    }
    __syncthreads();

    // ---- register state ----
    f32x2 v1r[3][6];
#pragma unroll
    for (int s = 0; s < 3; ++s)
#pragma unroll
        for (int j = 0; j < 6; ++j) v1r[s][j] = (f32x2){0.0f, 0.0f};
    f32x2 v2r2[8];                             // .x = row oyb, .y = row oyb+1, col j, co=lane
#pragma unroll
    for (int j = 0; j < 8; ++j) v2r2[j] = (f32x2){0.0f, 0.0f};

    const float b2v = b2g[lane];
    const f32x2 b2p = (f32x2){b2v, b2v};

    const int y0 = tid / 24,  x0 = tid - y0 * 24;
    const int p1i = tid + 256;
    const int y1 = p1i / 24,  x1 = p1i - y1 * 24;
    const int has2 = (tid < 64);
    const int p2i = tid + 512;
    const int y2 = p2i / 24,  x2 = p2i - y2 * 24;

    // ---- time loop: ONE barrier per step ----
    for (int t = 0; t < 80; ++t) {
        const float th = th_lds[t];

        // phase 1: gather input events into v1 reg pairs (unroll-4 prefetch)
        {
            const int e0 = off[t], e1t = off[t + 1];
            int e = e0;
            for (; e + 4 <= e1t; e += 4) {
                const unsigned a0 = evlist[e];
                const unsigned a1 = evlist[e + 1];
                const unsigned a2 = evlist[e + 2];
                const unsigned a3 = evlist[e + 3];
                P1EVENT(a0); P1EVENT(a1); P1EVENT(a2); P1EVENT(a3);
            }
            for (; e < e1t; ++e) { const unsigned a = evlist[e]; P1EVENT(a); }
        }
        CHECK_V1G(0, y0, x0);
        CHECK_V1G(1, y1, x1);
        if (has2) CHECK_V1G(2, y2, x2);
        __syncthreads();                       // B1: ev1b[t&1]/cnt1[t] complete

        // phase 2: pooled-l1 events -> v2 (4 events per ds_read_b64, paired-row loads)
        {
            const int ne1 = cnt1[t];
            const unsigned short* evp = ev1b[t & 1];
            if (USE_T) {
                int e = 0;
                for (; e + 4 <= ne1; e += 4) {
                    const unsigned long long pk4 = *(const unsigned long long*)&evp[e];
                    const unsigned lo = (unsigned)__builtin_amdgcn_readfirstlane((int)(unsigned)pk4);
                    const unsigned hi = (unsigned)__builtin_amdgcn_readfirstlane((int)(unsigned)(pk4 >> 32));
                    const int p0 = (int)(lo & 0xFFFFu), p1 = (int)(lo >> 16);
                    const int p2 = (int)(hi & 0xFFFFu), p3 = (int)(hi >> 16);
                    P2_ONE(p0); P2_ONE(p1); P2_ONE(p2); P2_ONE(p3);
                }
                for (; e < ne1; ++e) {
                    const int p0 = __builtin_amdgcn_readfirstlane((int)evp[e]);
                    P2_ONE(p0);
                }
            } else {
                for (int e = 0; e < ne1; ++e) {
                    const int pk = __builtin_amdgcn_readfirstlane((int)evp[e]);
                    const int dy0 = ((pk >> 4) & 15) - oyb_s;
                    if ((unsigned)dy0 >= 6u) continue;
                    const int ci = pk >> 8;
                    const int px = pk & 15;
                    const int dy1 = dy0 - 1;
                    const unsigned colm = ((0x1Fu << px) >> 4) & 0xFFu;
                    const unsigned m0 = ((unsigned)dy0 < 5u) ? colm : 0u;
                    const unsigned m1 = ((unsigned)dy1 < 5u) ? colm : 0u;
                    const int dy0c = dy0 < 0 ? 0 : (dy0 > 4 ? 4 : dy0);
                    const int dy1c = dy1 < 0 ? 0 : (dy1 > 4 ? 4 : dy1);
                    const float* cb = w2raw + lane * 300 + ci * 25;
                    const float* r0 = cb + dy0c * 5;
                    const float* r1 = cb + dy1c * 5;
#pragma unroll
                    for (int j = 0; j < 8; ++j) {
                        const int dx = px - j;
                        const int dxc = dx < 0 ? 0 : (dx > 4 ? 4 : dx);
                        v2r2[j].x = fmaf(r0[dxc], ((m0 >> j) & 1u) ? 1.0f : 0.0f, v2r2[j].x);
                        v2r2[j].y = fmaf(r1[dxc], ((m1 >> j) & 1u) ? 1.0f : 0.0f, v2r2[j].y);
                    }
                }
            }
        }
        // layer2: stepwise bias pk-add + max-screen + rare exact pass
        {
            PKADD(v2r2[0], b2p); PKADD(v2r2[1], b2p);
            PKADD(v2r2[2], b2p); PKADD(v2r2[3], b2p);
            PKADD(v2r2[4], b2p); PKADD(v2r2[5], b2p);
            PKADD(v2r2[6], b2p); PKADD(v2r2[7], b2p);
            float m2 = fmaxf(fmaxf(fmaxf(v2r2[0].x, v2r2[0].y), fmaxf(v2r2[1].x, v2r2[1].y)),
                             fmaxf(fmaxf(v2r2[2].x, v2r2[2].y), fmaxf(v2r2[3].x, v2r2[3].y)));
            m2 = fmaxf(m2, fmaxf(fmaxf(fmaxf(v2r2[4].x, v2r2[4].y), fmaxf(v2r2[5].x, v2r2[5].y)),
                                 fmaxf(fmaxf(v2r2[6].x, v2r2[6].y), fmaxf(v2r2[7].x, v2r2[7].y))));
            if (m2 >= th) {
#pragma unroll
                for (int j = 0; j < 8; ++j) {
#pragma unroll
                    for (int el = 0; el < 2; ++el) {
                        const float v = el ? v2r2[j].y : v2r2[j].x;
                        if (v >= th) {
                            if (el) v2r2[j].y = -__builtin_inff();
                            else    v2r2[j].x = -__builtin_inff();
                            const int oy = oyb_s + el;
                            const int p2 = ((oy >> 1) * 4 + (j >> 1)) * 64 + lane;  // NHWC flat
                            const unsigned bit = 1u << (p2 & 31);
                            const unsigned old = atomicOr(&pm2[p2 >> 5], bit);
                            if (!(old & bit)) {
                                const int pos = atomicAdd(&e2_cnt, 1);
                                e2list[pos] = ((unsigned)t << 16) | (unsigned)p2;
                            }
                        }
                    }
                }
            }
        }
        // no second barrier: next step's phase 1 touches only ev1b[(t+1)&1]/cnt1[t+1]
    }
    __syncthreads();                           // e2list complete

    // ---- output layer: replay t-sorted layer2 event log (no feedback) ----
    if (tid < 10) {
        const int n2 = e2_cnt;
        const float b3v = b3g[tid];
        float v = 0.0f;
        float ot = NOT_FIREDf;
        int ptr = 0;
        for (int t = 0; t < 80; ++t) {
            float acc = 0.0f;
            while (ptr < n2 && (int)(e2list[ptr] >> 16) == t) {
                acc += fcw[(e2list[ptr] & 0xFFFFu) * 10 + tid];
                ++ptr;
            }
            v += acc + b3v;
            if (ot == NOT_FIREDf && v >= th_lds[t]) ot = (float)t;
        }
        out[bimg * 10 + tid] = ot;
    }
}

extern "C" void kernel_launch(void* const* d_in, const int* in_sizes, int n_in,
                              void* d_out, int out_size, void* d_ws, size_t ws_size,
                              hipStream_t stream) {
    const float* img = (const float*)d_in[0];
    const float* w1  = (const float*)d_in[1];
    const float* b1  = (const float*)d_in[2];
    const float* w2  = (const float*)d_in[3];
    const float* b2  = (const float*)d_in[4];
    const float* fcw = (const float*)d_in[5];
    const float* b3  = (const float*)d_in[6];
    float* out = (float*)d_out;

    const int B = in_sizes[0] / (28 * 28);

    f32x2* w2q = (f32x2*)d_ws;
    const int use_t = (ws_size >= 175104u * sizeof(float)) ? 1 : 0;
    if (use_t) {
        hipLaunchKernelGGL(w2q_pad_kernel, dim3(684), dim3(256), 0, stream,
                           w2, (float*)d_ws);
        hipLaunchKernelGGL(snn_sim_kernel<1>, dim3(B), dim3(256), 0, stream,
                           img, w1, b1, b2, w2, w2q, fcw, b3, out);
    } else {
        hipLaunchKernelGGL(snn_sim_kernel<0>, dim3(B), dim3(256), 0, stream,
                           img, w1, b1, b2, w2, w2q, fcw, b3, out);
    }
}

// Round 17
// 3247.668 us; speedup vs baseline: 1.4502x; 1.4502x over previous
//
#include <hip/hip_runtime.h>
#include <math.h>

#define NOT_FIREDf 9999.0f
typedef float f32x2 __attribute__((ext_vector_type(2)));

// packed f32x2 add (bit-exact element-wise IEEE add, 1 inst for 2 adds)
#define PKADD(ACC, W) asm("v_pk_add_f32 %0, %0, %1" : "+v"(ACC) : "v"(W))

// Zero-padded conv2 weights in d_ws:
// w2p[((ci*5 + dy)*19 + rx)*64 + co] = (rx-7 in [0,5)) ? w2[(co*12+ci)*25 + dy*5 + (rx-7)] : 0
// plus a 19*64 zero row at w2p + 72960.
__global__ void w2_pad_kernel(const float* __restrict__ w2, float* __restrict__ w2p) {
    int idx = blockIdx.x * 256 + threadIdx.x;
    if (idx >= 74176) return;
    if (idx >= 72960) { w2p[idx] = 0.0f; return; }
    int co = idx & 63;
    int r = idx >> 6;            // ci*95 + dy*19 + rx
    int rx = r % 19;
    int q = r / 19;
    int dy = q % 5;
    int ci = q / 5;
    int dx = rx - 7;
    w2p[idx] = ((unsigned)dx < 5u) ? w2[(co * 12 + ci) * 25 + dy * 5 + dx] : 0.0f;
}

// v1 gather: 6 pk-adds of one w1 row (12 ch) into reg pairs
#define GATHER_V1(S, Y, X) do {                                              \
    const int dy_ = py - (Y), dx_ = px - (X);                                \
    if (((unsigned)dy_ < 5u) & ((unsigned)dx_ < 5u)) {                       \
        const f32x2* wp_ = (const f32x2*)&w1s[(dy_ * 5 + dx_) * 12];         \
        PKADD(v1r[S][0], wp_[0]); PKADD(v1r[S][1], wp_[1]);                  \
        PKADD(v1r[S][2], wp_[2]); PKADD(v1r[S][3], wp_[3]);                  \
        PKADD(v1r[S][4], wp_[4]); PKADD(v1r[S][5], wp_[5]);                  \
    } } while (0)

#define P1EVENT(PK) do {                                                     \
    const int py = (int)((PK) >> 8);                                         \
    const int px = (int)((PK) & 255u);                                       \
    GATHER_V1(0, y0, x0);                                                    \
    GATHER_V1(1, y1, x1);                                                    \
    if (has2) GATHER_V1(2, y2, x2);                                          \
  } while (0)

// stepwise bias pk-add (biases read from LDS, no persistent regs) + max-screen
#define CHECK_V1G(S, Y, X) do {                                              \
    const f32x2* bp_ = (const f32x2*)b1s;                                    \
    PKADD(v1r[S][0], bp_[0]); PKADD(v1r[S][1], bp_[1]);                      \
    PKADD(v1r[S][2], bp_[2]); PKADD(v1r[S][3], bp_[3]);                      \
    PKADD(v1r[S][4], bp_[4]); PKADD(v1r[S][5], bp_[5]);                      \
    float m_ = fmaxf(fmaxf(fmaxf(v1r[S][0].x, v1r[S][0].y),                  \
                           fmaxf(v1r[S][1].x, v1r[S][1].y)),                 \
                     fmaxf(fmaxf(v1r[S][2].x, v1r[S][2].y),                  \
                           fmaxf(v1r[S][3].x, v1r[S][3].y)));                \
    m_ = fmaxf(m_, fmaxf(fmaxf(v1r[S][4].x, v1r[S][4].y),                    \
                         fmaxf(v1r[S][5].x, v1r[S][5].y)));                  \
    if (m_ >= th) {                                                          \
        _Pragma("unroll")                                                    \
        for (int jj = 0; jj < 6; ++jj) {                                     \
            _Pragma("unroll")                                                \
            for (int el = 0; el < 2; ++el) {                                 \
                const float v_ = el ? v1r[S][jj].y : v1r[S][jj].x;           \
                if (v_ >= th) {                                              \
                    if (el) v1r[S][jj].y = -__builtin_inff();                \
                    else    v1r[S][jj].x = -__builtin_inff();                \
                    const int c_ = jj * 2 + el;                              \
                    const int pyp_ = (Y) >> 1, pxp_ = (X) >> 1;              \
                    const int p_ = c_ * 144 + pyp_ * 12 + pxp_;              \
                    const unsigned bit_ = 1u << (p_ & 31);                   \
                    const unsigned old_ = atomicOr(&pm1[p_ >> 5], bit_);     \
                    if (!(old_ & bit_)) {                                    \
                        const int pos_ = atomicAdd(&cnt1[t], 1);             \
                        ev1b[t & 1][pos_] =                                  \
                            (unsigned short)((c_ << 8) | (pyp_ << 4) | pxp_);\
                    }                                                        \
                }                                                            \
            }                                                                \
        }                                                                    \
    } } while (0)

// one phase-2 event: two la_[4] half-batches (8 live temps instead of 16);
// per-accumulator FP order unchanged (one weight add per event)
#define P2_ONE(PA) do {                                                      \
    const int dA_ = (((PA) >> 4) & 15) - oyb_s;                              \
    if ((unsigned)dA_ < 6u) {                                                \
        const int ci_ = (PA) >> 8;                                           \
        const int px_ = (PA) & 15;                                           \
        const float* r0_ = (dA_ <= 4) ? (w2p + (ci_ * 5 + dA_) * 1216) : zrow; \
        const float* r1_ = (dA_ >= 1) ? (w2p + (ci_ * 5 + dA_ - 1) * 1216) : zrow; \
        const float* q0_ = r0_ + (px_ + 7) * 64 + lane;                      \
        const float* q1_ = r1_ + (px_ + 7) * 64 + lane;                      \
        f32x2 la_[4];                                                        \
        _Pragma("unroll")                                                    \
        for (int j = 0; j < 4; ++j) { la_[j].x = q0_[-(j * 64)]; la_[j].y = q1_[-(j * 64)]; } \
        _Pragma("unroll")                                                    \
        for (int j = 0; j < 4; ++j) PKADD(v2r2[j], la_[j]);                  \
        _Pragma("unroll")                                                    \
        for (int j = 0; j < 4; ++j) { la_[j].x = q0_[-((4 + j) * 64)]; la_[j].y = q1_[-((4 + j) * 64)]; } \
        _Pragma("unroll")                                                    \
        for (int j = 0; j < 4; ++j) PKADD(v2r2[4 + j], la_[j]);              \
    } } while (0)

template <int USE_T>
__global__ void __launch_bounds__(256, 4)
snn_sim_kernel(const float* __restrict__ img,
               const float* __restrict__ w1g,
               const float* __restrict__ b1g,
               const float* __restrict__ b2g,
               const float* __restrict__ w2raw,
               const float* __restrict__ w2p,
               const float* __restrict__ fcw,
               const float* __restrict__ b3g,
               float* __restrict__ out) {
    const int bimg = blockIdx.x;
    const int tid  = threadIdx.x;
    const int lane = tid & 63;
    const int wv   = tid >> 6;   // 4 waves
    const int oyb_s = __builtin_amdgcn_readfirstlane(wv) * 2;   // wave-uniform SGPR

    __shared__ __align__(16) float w1s[300];   // transposed: [k=ky*5+kx][c]
    __shared__ __align__(8)  float b1s[12];
    __shared__ float th_lds[80];
    __shared__ unsigned char  stin[784];
    __shared__ unsigned short evlist[784];     // t-sorted schedule, packed (py<<8|px)
    __shared__ unsigned short off[81];
    __shared__ unsigned int   hist[80];
    __shared__ __align__(8) unsigned short ev1b[2][1728];  // pooled-l1 events, dbuf
    __shared__ int            cnt1[80];        // per-step counters, never reset
    __shared__ unsigned int   pm1[54];
    __shared__ unsigned int   pm2[32];
    __shared__ unsigned int   e2list[1024];    // persistent: (t<<16) | nhwc_flat_idx
    __shared__ int            e2_cnt;

    // ---- init ----
    for (int i = tid; i < 300; i += 256) {
        int k = i / 12, c = i - k * 12;
        w1s[i] = w1g[c * 25 + k];
    }
    if (tid < 12) b1s[tid] = b1g[tid];
    if (tid < 80) {
        float xa = (0.0f - (float)tid) / 20.0f;
        th_lds[tid] = (float)exp((double)xa);            // correctly-rounded f32 exp
        hist[tid] = 0u;
        cnt1[tid] = 0;
    }
    if (tid < 54) pm1[tid] = 0u;
    if (tid < 32) pm2[tid] = 0u;
    if (tid == 0) e2_cnt = 0;
    for (int i = tid; i < 784; i += 256) {
        float p = img[bimg * 784 + i];
        p = fmaxf(p, 1e-5f);
        float lg = (float)log((double)p);                // correctly-rounded f32 log
        float s = ceilf(fmaxf(-17.452274f * lg, 0.0f));
        stin[i] = (unsigned char)(int)fminf(s, 255.0f);
    }
    __syncthreads();
    for (int i = tid; i < 784; i += 256) {
        int t = stin[i];
        if (t < 80) atomicAdd(&hist[t], 1u);
    }
    __syncthreads();
    if (tid == 0) {
        unsigned int acc = 0;
        for (int t = 0; t < 80; ++t) { off[t] = (unsigned short)acc; acc += hist[t]; }
        off[80] = (unsigned short)acc;
    }
    __syncthreads();
    if (tid < 80) {                            // deterministic pixel-order fill per t-bin
        int k = off[tid];
        for (int i = 0; i < 784; ++i)
            if ((int)stin[i] == tid) {
                int py = i / 28;
                evlist[k++] = (unsigned short)((py << 8) | (i - py * 28));
            }
    }
    __syncthreads();

    // ---- register state ----
    f32x2 v1r[3][6];
#pragma unroll
    for (int s = 0; s < 3; ++s)
#pragma unroll
        for (int j = 0; j < 6; ++j) v1r[s][j] = (f32x2){0.0f, 0.0f};
    f32x2 v2r2[8];                             // .x = row oyb, .y = row oyb+1, col j, co=lane
#pragma unroll
    for (int j = 0; j < 8; ++j) v2r2[j] = (f32x2){0.0f, 0.0f};

    const float b2v = b2g[lane];
    const f32x2 b2p = (f32x2){b2v, b2v};
    const float* zrow = w2p + 72960;

    const int y0 = tid / 24,  x0 = tid - y0 * 24;
    const int p1i = tid + 256;
    const int y1 = p1i / 24,  x1 = p1i - y1 * 24;
    const int has2 = (tid < 64);
    const int p2i = tid + 512;
    const int y2 = p2i / 24,  x2 = p2i - y2 * 24;

    // ---- time loop: ONE barrier per step ----
    for (int t = 0; t < 80; ++t) {
        const float th = th_lds[t];

        // phase 1: gather input events into v1 reg pairs (unroll-4 prefetch)
        {
            const int e0 = off[t], e1t = off[t + 1];
            int e = e0;
            for (; e + 4 <= e1t; e += 4) {
                const unsigned a0 = evlist[e];
                const unsigned a1 = evlist[e + 1];
                const unsigned a2 = evlist[e + 2];
                const unsigned a3 = evlist[e + 3];
                P1EVENT(a0); P1EVENT(a1); P1EVENT(a2); P1EVENT(a3);
            }
            for (; e < e1t; ++e) { const unsigned a = evlist[e]; P1EVENT(a); }
        }
        CHECK_V1G(0, y0, x0);
        CHECK_V1G(1, y1, x1);
        if (has2) CHECK_V1G(2, y2, x2);
        __syncthreads();                       // B1: ev1b[t&1]/cnt1[t] complete

        // phase 2: pooled-l1 events -> v2 (4 events per ds_read_b64)
        {
            const int ne1 = cnt1[t];
            const unsigned short* evp = ev1b[t & 1];
            if (USE_T) {
                int e = 0;
                for (; e + 4 <= ne1; e += 4) {
                    const unsigned long long pk4 = *(const unsigned long long*)&evp[e];
                    const unsigned lo = (unsigned)__builtin_amdgcn_readfirstlane((int)(unsigned)pk4);
                    const unsigned hi = (unsigned)__builtin_amdgcn_readfirstlane((int)(unsigned)(pk4 >> 32));
                    const int p0 = (int)(lo & 0xFFFFu), p1 = (int)(lo >> 16);
                    const int p2 = (int)(hi & 0xFFFFu), p3 = (int)(hi >> 16);
                    P2_ONE(p0); P2_ONE(p1); P2_ONE(p2); P2_ONE(p3);
                }
                for (; e < ne1; ++e) {
                    const int p0 = __builtin_amdgcn_readfirstlane((int)evp[e]);
                    P2_ONE(p0);
                }
            } else {
                for (int e = 0; e < ne1; ++e) {
                    const int pk = __builtin_amdgcn_readfirstlane((int)evp[e]);
                    const int dy0 = ((pk >> 4) & 15) - oyb_s;
                    if ((unsigned)dy0 >= 6u) continue;
                    const int ci = pk >> 8;
                    const int px = pk & 15;
                    const int dy1 = dy0 - 1;
                    const unsigned colm = ((0x1Fu << px) >> 4) & 0xFFu;
                    const unsigned m0 = ((unsigned)dy0 < 5u) ? colm : 0u;
                    const unsigned m1 = ((unsigned)dy1 < 5u) ? colm : 0u;
                    const int dy0c = dy0 < 0 ? 0 : (dy0 > 4 ? 4 : dy0);
                    const int dy1c = dy1 < 0 ? 0 : (dy1 > 4 ? 4 : dy1);
                    const float* cb = w2raw + lane * 300 + ci * 25;
                    const float* r0 = cb + dy0c * 5;
                    const float* r1 = cb + dy1c * 5;
#pragma unroll
                    for (int j = 0; j < 8; ++j) {
                        const int dx = px - j;
                        const int dxc = dx < 0 ? 0 : (dx > 4 ? 4 : dx);
                        v2r2[j].x = fmaf(r0[dxc], ((m0 >> j) & 1u) ? 1.0f : 0.0f, v2r2[j].x);
                        v2r2[j].y = fmaf(r1[dxc], ((m1 >> j) & 1u) ? 1.0f : 0.0f, v2r2[j].y);
                    }
                }
            }
        }
        // layer2: stepwise bias pk-add + max-screen + rare exact pass
        {
            PKADD(v2r2[0], b2p); PKADD(v2r2[1], b2p);
            PKADD(v2r2[2], b2p); PKADD(v2r2[3], b2p);
            PKADD(v2r2[4], b2p); PKADD(v2r2[5], b2p);
            PKADD(v2r2[6], b2p); PKADD(v2r2[7], b2p);
            float m2 = fmaxf(fmaxf(fmaxf(v2r2[0].x, v2r2[0].y), fmaxf(v2r2[1].x, v2r2[1].y)),
                             fmaxf(fmaxf(v2r2[2].x, v2r2[2].y), fmaxf(v2r2[3].x, v2r2[3].y)));
            m2 = fmaxf(m2, fmaxf(fmaxf(fmaxf(v2r2[4].x, v2r2[4].y), fmaxf(v2r2[5].x, v2r2[5].y)),
                                 fmaxf(fmaxf(v2r2[6].x, v2r2[6].y), fmaxf(v2r2[7].x, v2r2[7].y))));
            if (m2 >= th) {
#pragma unroll
                for (int j = 0; j < 8; ++j) {
#pragma unroll
                    for (int el = 0; el < 2; ++el) {
                        const float v = el ? v2r2[j].y : v2r2[j].x;
                        if (v >= th) {
                            if (el) v2r2[j].y = -__builtin_inff();
                            else    v2r2[j].x = -__builtin_inff();
                            const int oy = oyb_s + el;
                            const int p2 = ((oy >> 1) * 4 + (j >> 1)) * 64 + lane;  // NHWC flat
                            const unsigned bit = 1u << (p2 & 31);
                            const unsigned old = atomicOr(&pm2[p2 >> 5], bit);
                            if (!(old & bit)) {
                                const int pos = atomicAdd(&e2_cnt, 1);
                                e2list[pos] = ((unsigned)t << 16) | (unsigned)p2;
                            }
                        }
                    }
                }
            }
        }
        // no second barrier: next step's phase 1 touches only ev1b[(t+1)&1]/cnt1[t+1]
    }
    __syncthreads();                           // e2list complete

    // ---- output layer: replay t-sorted layer2 event log (no feedback) ----
    if (tid < 10) {
        const int n2 = e2_cnt;
        const float b3v = b3g[tid];
        float v = 0.0f;
        float ot = NOT_FIREDf;
        int ptr = 0;
        for (int t = 0; t < 80; ++t) {
            float acc = 0.0f;
            while (ptr < n2 && (int)(e2list[ptr] >> 16) == t) {
                acc += fcw[(e2list[ptr] & 0xFFFFu) * 10 + tid];
                ++ptr;
            }
            v += acc + b3v;
            if (ot == NOT_FIREDf && v >= th_lds[t]) ot = (float)t;
        }
        out[bimg * 10 + tid] = ot;
    }
}

extern "C" void kernel_launch(void* const* d_in, const int* in_sizes, int n_in,
                              void* d_out, int out_size, void* d_ws, size_t ws_size,
                              hipStream_t stream) {
    const float* img = (const float*)d_in[0];
    const float* w1  = (const float*)d_in[1];
    const float* b1  = (const float*)d_in[2];
    const float* w2  = (const float*)d_in[3];
    const float* b2  = (const float*)d_in[4];
    const float* fcw = (const float*)d_in[5];
    const float* b3  = (const float*)d_in[6];
    float* out = (float*)d_out;

    const int B = in_sizes[0] / (28 * 28);

    float* w2p = (float*)d_ws;
    const int use_t = (ws_size >= 74176u * sizeof(float)) ? 1 : 0;
    if (use_t) {
        hipLaunchKernelGGL(w2_pad_kernel, dim3(290), dim3(256), 0, stream, w2, w2p);
        hipLaunchKernelGGL(snn_sim_kernel<1>, dim3(B), dim3(256), 0, stream,
                           img, w1, b1, b2, w2, w2p, fcw, b3, out);
    } else {
        hipLaunchKernelGGL(snn_sim_kernel<0>, dim3(B), dim3(256), 0, stream,
                           img, w1, b1, b2, w2, w2p, fcw, b3, out);
    }
}

// Round 19
// 2873.409 us; speedup vs baseline: 1.6391x; 1.1302x over previous
//
#include <hip/hip_runtime.h>
#include <math.h>

#define NOT_FIREDf 9999.0f
typedef float f32x2 __attribute__((ext_vector_type(2)));

// packed f32x2 add (bit-exact element-wise IEEE add, 1 inst for 2 adds)
#define PKADD(ACC, W) asm("v_pk_add_f32 %0, %0, %1" : "+v"(ACC) : "v"(W))

// Zero-padded conv2 weights in d_ws:
// w2p[((ci*5 + dy)*19 + rx)*64 + co] = (rx-7 in [0,5)) ? w2[(co*12+ci)*25 + dy*5 + (rx-7)] : 0
// plus a 19*64 zero row at w2p + 72960.
__global__ void w2_pad_kernel(const float* __restrict__ w2, float* __restrict__ w2p) {
    int idx = blockIdx.x * 256 + threadIdx.x;
    if (idx >= 74176) return;
    if (idx >= 72960) { w2p[idx] = 0.0f; return; }
    int co = idx & 63;
    int r = idx >> 6;            // ci*95 + dy*19 + rx
    int rx = r % 19;
    int q = r / 19;
    int dy = q % 5;
    int ci = q / 5;
    int dx = rx - 7;
    w2p[idx] = ((unsigned)dx < 5u) ? w2[(co * 12 + ci) * 25 + dy * 5 + dx] : 0.0f;
}

// v1 gather: 6 pk-adds of one w1 row (12 ch) into reg pairs
#define GATHER_V1(S, Y, X) do {                                              \
    const int dy_ = py - (Y), dx_ = px - (X);                                \
    if (((unsigned)dy_ < 5u) & ((unsigned)dx_ < 5u)) {                       \
        const f32x2* wp_ = (const f32x2*)&w1s[(dy_ * 5 + dx_) * 12];         \
        PKADD(v1r[S][0], wp_[0]); PKADD(v1r[S][1], wp_[1]);                  \
        PKADD(v1r[S][2], wp_[2]); PKADD(v1r[S][3], wp_[3]);                  \
        PKADD(v1r[S][4], wp_[4]); PKADD(v1r[S][5], wp_[5]);                  \
    } } while (0)

#define P1EVENT(PK) do {                                                     \
    const int py = (int)((PK) >> 8);                                         \
    const int px = (int)((PK) & 255u);                                       \
    GATHER_V1(0, y0, x0);                                                    \
    GATHER_V1(1, y1, x1);                                                    \
    if (has2) GATHER_V1(2, y2, x2);                                          \
  } while (0)

// stepwise bias pk-add + max-screen; on fire, write fire-time byte to the
// exclusively-owned f1 slot (no atomics, no event append — sorted later)
#define CHECK_V1F(S, Y, X) do {                                              \
    const f32x2* bp_ = (const f32x2*)b1s;                                    \
    PKADD(v1r[S][0], bp_[0]); PKADD(v1r[S][1], bp_[1]);                      \
    PKADD(v1r[S][2], bp_[2]); PKADD(v1r[S][3], bp_[3]);                      \
    PKADD(v1r[S][4], bp_[4]); PKADD(v1r[S][5], bp_[5]);                      \
    float m_ = fmaxf(fmaxf(fmaxf(v1r[S][0].x, v1r[S][0].y),                  \
                           fmaxf(v1r[S][1].x, v1r[S][1].y)),                 \
                     fmaxf(fmaxf(v1r[S][2].x, v1r[S][2].y),                  \
                           fmaxf(v1r[S][3].x, v1r[S][3].y)));                \
    m_ = fmaxf(m_, fmaxf(fmaxf(v1r[S][4].x, v1r[S][4].y),                    \
                         fmaxf(v1r[S][5].x, v1r[S][5].y)));                  \
    if (m_ >= th) {                                                          \
        _Pragma("unroll")                                                    \
        for (int jj = 0; jj < 6; ++jj) {                                     \
            _Pragma("unroll")                                                \
            for (int el = 0; el < 2; ++el) {                                 \
                const float v_ = el ? v1r[S][jj].y : v1r[S][jj].x;           \
                if (v_ >= th) {                                              \
                    if (el) v1r[S][jj].y = -__builtin_inff();                \
                    else    v1r[S][jj].x = -__builtin_inff();                \
                    const int c_ = jj * 2 + el;                              \
                    const int pyp_ = (Y) >> 1, pxp_ = (X) >> 1;              \
                    const int bidx_ = ((c_ * 144 + pyp_ * 12 + pxp_) << 2)   \
                                    | (((Y) & 1) << 1) | ((X) & 1);          \
                    f1b[bidx_] = (unsigned char)t;                           \
                }                                                            \
            }                                                                \
        }                                                                    \
    } } while (0)

// one phase-2 event: two la_[4] half-batches; order per accumulator unchanged
#define P2_ONE(PA) do {                                                      \
    const int dA_ = (((PA) >> 4) & 15) - oyb_s;                              \
    if ((unsigned)dA_ < 6u) {                                                \
        const int ci_ = (PA) >> 8;                                           \
        const int px_ = (PA) & 15;                                           \
        const float* r0_ = (dA_ <= 4) ? (w2p + (ci_ * 5 + dA_) * 1216) : zrow; \
        const float* r1_ = (dA_ >= 1) ? (w2p + (ci_ * 5 + dA_ - 1) * 1216) : zrow; \
        const float* q0_ = r0_ + (px_ + 7) * 64 + lane;                      \
        const float* q1_ = r1_ + (px_ + 7) * 64 + lane;                      \
        f32x2 la_[4];                                                        \
        _Pragma("unroll")                                                    \
        for (int j = 0; j < 4; ++j) { la_[j].x = q0_[-(j * 64)]; la_[j].y = q1_[-(j * 64)]; } \
        _Pragma("unroll")                                                    \
        for (int j = 0; j < 4; ++j) PKADD(v2r2[j], la_[j]);                  \
        _Pragma("unroll")                                                    \
        for (int j = 0; j < 4; ++j) { la_[j].x = q0_[-((4 + j) * 64)]; la_[j].y = q1_[-((4 + j) * 64)]; } \
        _Pragma("unroll")                                                    \
        for (int j = 0; j < 4; ++j) PKADD(v2r2[4 + j], la_[j]);              \
    } } while (0)

__device__ __forceinline__ unsigned min4b(unsigned w) {
    unsigned a = w & 255u, b = (w >> 8) & 255u, c = (w >> 16) & 255u, d = w >> 24;
    unsigned m0 = a < b ? a : b;
    unsigned m1 = c < d ? c : d;
    return m0 < m1 ? m0 : m1;
}

template <int USE_T>
__global__ void __launch_bounds__(256, 4)
snn_sim_kernel(const float* __restrict__ img,
               const float* __restrict__ w1g,
               const float* __restrict__ b1g,
               const float* __restrict__ b2g,
               const float* __restrict__ w2raw,
               const float* __restrict__ w2p,
               const float* __restrict__ fcw,
               const float* __restrict__ b3g,
               float* __restrict__ out) {
    const int bimg = blockIdx.x;
    const int tid  = threadIdx.x;
    const int lane = tid & 63;
    const int wv   = tid >> 6;   // 4 waves
    const int oyb_s = __builtin_amdgcn_readfirstlane(wv) * 2;   // wave-uniform SGPR
    const int wv_s  = oyb_s >> 1;

    __shared__ __align__(16) float w1s[300];   // transposed: [k=ky*5+kx][c]
    __shared__ __align__(8)  float b1s[12];
    __shared__ float th_lds[80];
    __shared__ unsigned char  stin[784];
    __shared__ unsigned short evlist[784];     // t-sorted input schedule (py<<8|px)
    __shared__ unsigned short off[81];         // input offsets; reused for e2 offsets
    __shared__ unsigned short o1[81];          // l1 event offsets
    __shared__ unsigned int   hist[80];
    __shared__ unsigned int   f1w[1728];       // l1 fire times: 4 constituent bytes / pooled loc
    __shared__ __align__(8) unsigned short ev1s[1728]; // sorted l1 events; reused as sorted e2
    __shared__ unsigned char  e2t[1024];       // l2 pooled fire time per NHWC flat idx

    unsigned char* f1b = (unsigned char*)f1w;

    // ---- init ----
    for (int i = tid; i < 300; i += 256) {
        int k = i / 12, c = i - k * 12;
        w1s[i] = w1g[c * 25 + k];
    }
    if (tid < 12) b1s[tid] = b1g[tid];
    if (tid < 80) {
        float xa = (0.0f - (float)tid) / 20.0f;
        th_lds[tid] = (float)exp((double)xa);            // correctly-rounded f32 exp
        hist[tid] = 0u;
    }
    for (int i = tid; i < 1728; i += 256) f1w[i] = 0xFFFFFFFFu;
    for (int i = tid; i < 1024; i += 256) e2t[i] = 0xFF;
    for (int i = tid; i < 784; i += 256) {
        float p = img[bimg * 784 + i];
        p = fmaxf(p, 1e-5f);
        float lg = (float)log((double)p);                // correctly-rounded f32 log
        float s = ceilf(fmaxf(-17.452274f * lg, 0.0f));
        stin[i] = (unsigned char)(int)fminf(s, 255.0f);
    }
    __syncthreads();
    for (int i = tid; i < 784; i += 256) {
        int t = stin[i];
        if (t < 80) atomicAdd(&hist[t], 1u);
    }
    __syncthreads();
    if (tid == 0) {
        unsigned int acc = 0;
        for (int t = 0; t < 80; ++t) { off[t] = (unsigned short)acc; acc += hist[t]; }
        off[80] = (unsigned short)acc;
    }
    __syncthreads();
    if (tid < 80) {                            // deterministic pixel-order fill per t-bin
        int k = off[tid];
        for (int i = 0; i < 784; ++i)
            if ((int)stin[i] == tid) {
                int py = i / 28;
                evlist[k++] = (unsigned short)((py << 8) | (i - py * 28));
            }
    }
    if (tid >= 80 && tid < 160) hist[tid - 80] = 0u;     // reset for l1 counting
    __syncthreads();

    // ================= PASS A: layer 1, all 80 steps, NO barriers =================
    {
        f32x2 v1r[3][6];
#pragma unroll
        for (int s = 0; s < 3; ++s)
#pragma unroll
            for (int j = 0; j < 6; ++j) v1r[s][j] = (f32x2){0.0f, 0.0f};

        const int y0 = tid / 24,  x0 = tid - y0 * 24;
        const int p1i = tid + 256;
        const int y1 = p1i / 24,  x1 = p1i - y1 * 24;
        const int has2 = (tid < 64);
        const int p2i = tid + 512;
        const int y2 = p2i / 24,  x2 = p2i - y2 * 24;

        for (int t = 0; t < 80; ++t) {
            const float th = th_lds[t];
            const int e0 = off[t], e1t = off[t + 1];
            int e = e0;
            for (; e + 4 <= e1t; e += 4) {
                const unsigned a0 = evlist[e];
                const unsigned a1 = evlist[e + 1];
                const unsigned a2 = evlist[e + 2];
                const unsigned a3 = evlist[e + 3];
                P1EVENT(a0); P1EVENT(a1); P1EVENT(a2); P1EVENT(a3);
            }
            for (; e < e1t; ++e) { const unsigned a = evlist[e]; P1EVENT(a); }
            CHECK_V1F(0, y0, x0);
            CHECK_V1F(1, y1, x1);
            if (has2) CHECK_V1F(2, y2, x2);
        }
    }
    __syncthreads();                           // B1: f1 complete

    // ---- sort l1 pooled events by fire time (deterministic) ----
    for (int p = tid; p < 1728; p += 256) {
        unsigned tm = min4b(f1w[p]);
        if (tm < 80u) atomicAdd(&hist[tm], 1u);
    }
    __syncthreads();                           // B2
    if (tid == 0) {
        unsigned acc = 0;
        for (int t = 0; t < 80; ++t) { o1[t] = (unsigned short)acc; acc += hist[t]; }
        o1[80] = (unsigned short)acc;
    }
    __syncthreads();                           // B3
    if (tid < 80) {                            // deterministic p-order fill per t-bin
        int k = o1[tid];
        for (int p = 0; p < 1728; ++p) {
            if (min4b(f1w[p]) == (unsigned)tid) {
                int c = p / 144;
                int rem = p - c * 144;
                int py = rem / 12;
                int px = rem - py * 12;
                ev1s[k++] = (unsigned short)((c << 8) | (py << 4) | px);
            }
        }
    }
    // reset for e2 counting — safe here: nothing reads hist until after B5
    if (tid >= 80 && tid < 160) hist[tid - 80] = 0u;
    __syncthreads();                           // B4: ev1s/o1 ready

    // ================= PASS B: layer 2, all 80 steps, NO barriers =================
    {
        f32x2 v2r2[8];                         // .x = row oyb, .y = row oyb+1, col j, co=lane
#pragma unroll
        for (int j = 0; j < 8; ++j) v2r2[j] = (f32x2){0.0f, 0.0f};
        const float b2v = b2g[lane];
        const f32x2 b2p = (f32x2){b2v, b2v};
        const float* zrow = w2p + 72960;
        unsigned fired2 = 0u;                  // 4 pooled-l2 locs per thread, reg mask

        for (int t = 0; t < 80; ++t) {
            const float th = th_lds[t];
            const int e0 = o1[t], e1t = o1[t + 1];
            if (USE_T) {
                int e = e0;
                for (; e + 4 <= e1t; e += 4) {
                    const int p0 = __builtin_amdgcn_readfirstlane((int)ev1s[e]);
                    const int p1 = __builtin_amdgcn_readfirstlane((int)ev1s[e + 1]);
                    const int p2 = __builtin_amdgcn_readfirstlane((int)ev1s[e + 2]);
                    const int p3 = __builtin_amdgcn_readfirstlane((int)ev1s[e + 3]);
                    P2_ONE(p0); P2_ONE(p1); P2_ONE(p2); P2_ONE(p3);
                }
                for (; e < e1t; ++e) {
                    const int p0 = __builtin_amdgcn_readfirstlane((int)ev1s[e]);
                    P2_ONE(p0);
                }
            } else {
                for (int e = e0; e < e1t; ++e) {
                    const int pk = __builtin_amdgcn_readfirstlane((int)ev1s[e]);
                    const int dy0 = ((pk >> 4) & 15) - oyb_s;
                    if ((unsigned)dy0 >= 6u) continue;
                    const int ci = pk >> 8;
                    const int px = pk & 15;
                    const int dy1 = dy0 - 1;
                    const unsigned colm = ((0x1Fu << px) >> 4) & 0xFFu;
                    const unsigned m0 = ((unsigned)dy0 < 5u) ? colm : 0u;
                    const unsigned m1 = ((unsigned)dy1 < 5u) ? colm : 0u;
                    const int dy0c = dy0 < 0 ? 0 : (dy0 > 4 ? 4 : dy0);
                    const int dy1c = dy1 < 0 ? 0 : (dy1 > 4 ? 4 : dy1);
                    const float* cb = w2raw + lane * 300 + ci * 25;
                    const float* r0 = cb + dy0c * 5;
                    const float* r1 = cb + dy1c * 5;
#pragma unroll
                    for (int j = 0; j < 8; ++j) {
                        const int dx = px - j;
                        const int dxc = dx < 0 ? 0 : (dx > 4 ? 4 : dx);
                        v2r2[j].x = fmaf(r0[dxc], ((m0 >> j) & 1u) ? 1.0f : 0.0f, v2r2[j].x);
                        v2r2[j].y = fmaf(r1[dxc], ((m1 >> j) & 1u) ? 1.0f : 0.0f, v2r2[j].y);
                    }
                }
            }
            // layer2: stepwise bias pk-add + max-screen + rare exact pass
            PKADD(v2r2[0], b2p); PKADD(v2r2[1], b2p);
            PKADD(v2r2[2], b2p); PKADD(v2r2[3], b2p);
            PKADD(v2r2[4], b2p); PKADD(v2r2[5], b2p);
            PKADD(v2r2[6], b2p); PKADD(v2r2[7], b2p);
            float m2 = fmaxf(fmaxf(fmaxf(v2r2[0].x, v2r2[0].y), fmaxf(v2r2[1].x, v2r2[1].y)),
                             fmaxf(fmaxf(v2r2[2].x, v2r2[2].y), fmaxf(v2r2[3].x, v2r2[3].y)));
            m2 = fmaxf(m2, fmaxf(fmaxf(fmaxf(v2r2[4].x, v2r2[4].y), fmaxf(v2r2[5].x, v2r2[5].y)),
                                 fmaxf(fmaxf(v2r2[6].x, v2r2[6].y), fmaxf(v2r2[7].x, v2r2[7].y))));
            if (m2 >= th) {
#pragma unroll
                for (int j = 0; j < 8; ++j) {
#pragma unroll
                    for (int el = 0; el < 2; ++el) {
                        const float v = el ? v2r2[j].y : v2r2[j].x;
                        if (v >= th) {
                            if (el) v2r2[j].y = -__builtin_inff();
                            else    v2r2[j].x = -__builtin_inff();
                            const unsigned bit = 1u << (j >> 1);
                            if (!(fired2 & bit)) {
                                fired2 |= bit;
                                const int p2 = (wv_s * 4 + (j >> 1)) * 64 + lane;  // NHWC flat
                                e2t[p2] = (unsigned char)t;   // single write ever, race-free
                            }
                        }
                    }
                }
            }
        }
    }
    __syncthreads();                           // B5: e2t complete

    // ---- sort l2 events by fire time (deterministic) ----
    for (int p = tid; p < 1024; p += 256) {
        unsigned t = e2t[p];
        if (t < 80u) atomicAdd(&hist[t], 1u);
    }
    __syncthreads();                           // B6
    if (tid == 0) {
        unsigned acc = 0;
        for (int t = 0; t < 80; ++t) { off[t] = (unsigned short)acc; acc += hist[t]; }
        off[80] = (unsigned short)acc;
    }
    __syncthreads();                           // B7
    if (tid < 80) {                            // deterministic p2-order fill per t-bin
        int k = off[tid];
        for (int p = 0; p < 1024; ++p)
            if ((int)e2t[p] == tid) ev1s[k++] = (unsigned short)p;
    }
    __syncthreads();                           // B8

    // ---- output layer: replay t-sorted layer2 events (no feedback) ----
    if (tid < 10) {
        const float b3v = b3g[tid];
        float v = 0.0f;
        float ot = NOT_FIREDf;
        for (int t = 0; t < 80; ++t) {
            float acc = 0.0f;
            for (int e = off[t]; e < off[t + 1]; ++e)
                acc += fcw[(int)ev1s[e] * 10 + tid];
            v += acc + b3v;
            if (ot == NOT_FIREDf && v >= th_lds[t]) ot = (float)t;
        }
        out[bimg * 10 + tid] = ot;
    }
}

extern "C" void kernel_launch(void* const* d_in, const int* in_sizes, int n_in,
                              void* d_out, int out_size, void* d_ws, size_t ws_size,
                              hipStream_t stream) {
    const float* img = (const float*)d_in[0];
    const float* w1  = (const float*)d_in[1];
    const float* b1  = (const float*)d_in[2];
    const float* w2  = (const float*)d_in[3];
    const float* b2  = (const float*)d_in[4];
    const float* fcw = (const float*)d_in[5];
    const float* b3  = (const float*)d_in[6];
    float* out = (float*)d_out;

    const int B = in_sizes[0] / (28 * 28);

    float* w2p = (float*)d_ws;
    const int use_t = (ws_size >= 74176u * sizeof(float)) ? 1 : 0;
    if (use_t) {
        hipLaunchKernelGGL(w2_pad_kernel, dim3(290), dim3(256), 0, stream, w2, w2p);
        hipLaunchKernelGGL(snn_sim_kernel<1>, dim3(B), dim3(256), 0, stream,
                           img, w1, b1, b2, w2, w2p, fcw, b3, out);
    } else {
        hipLaunchKernelGGL(snn_sim_kernel<0>, dim3(B), dim3(256), 0, stream,
                           img, w1, b1, b2, w2, w2p, fcw, b3, out);
    }
}

// Round 20
// 2786.418 us; speedup vs baseline: 1.6903x; 1.0312x over previous
//
#include <hip/hip_runtime.h>
#include <math.h>

#define NOT_FIREDf 9999.0f
typedef float f32x2 __attribute__((ext_vector_type(2)));

// packed f32x2 add (bit-exact element-wise IEEE add, 1 inst for 2 adds)
#define PKADD(ACC, W) asm("v_pk_add_f32 %0, %0, %1" : "+v"(ACC) : "v"(W))

// Zero-padded conv2 weights in d_ws:
// w2p[((ci*5 + dy)*19 + rx)*64 + co] = (rx-7 in [0,5)) ? w2[(co*12+ci)*25 + dy*5 + (rx-7)] : 0
__global__ void w2_pad_kernel(const float* __restrict__ w2, float* __restrict__ w2p) {
    int idx = blockIdx.x * 256 + threadIdx.x;
    if (idx >= 72960) return;
    int co = idx & 63;
    int r = idx >> 6;            // ci*95 + dy*19 + rx
    int rx = r % 19;
    int q = r / 19;
    int dy = q % 5;
    int ci = q / 5;
    int dx = rx - 7;
    w2p[idx] = ((unsigned)dx < 5u) ? w2[(co * 12 + ci) * 25 + dy * 5 + dx] : 0.0f;
}

// v1 gather: 6 pk-adds of one w1 row (12 ch) into reg pairs
#define GATHER_V1(S, Y, X) do {                                              \
    const int dy_ = py - (Y), dx_ = px - (X);                                \
    if (((unsigned)dy_ < 5u) & ((unsigned)dx_ < 5u)) {                       \
        const f32x2* wp_ = (const f32x2*)&w1s[(dy_ * 5 + dx_) * 12];         \
        PKADD(v1r[S][0], wp_[0]); PKADD(v1r[S][1], wp_[1]);                  \
        PKADD(v1r[S][2], wp_[2]); PKADD(v1r[S][3], wp_[3]);                  \
        PKADD(v1r[S][4], wp_[4]); PKADD(v1r[S][5], wp_[5]);                  \
    } } while (0)

#define P1EVENT(PK) do {                                                     \
    const int py = (int)((PK) >> 8);                                         \
    const int px = (int)((PK) & 255u);                                       \
    GATHER_V1(0, y0, x0);                                                    \
    GATHER_V1(1, y1, x1);                                                    \
    if (has2) GATHER_V1(2, y2, x2);                                          \
  } while (0)

// stepwise bias pk-add + max-screen; on fire, write fire-time byte to the
// exclusively-owned f1 slot (no atomics, no event append — sorted later)
#define CHECK_V1F(S, Y, X) do {                                              \
    const f32x2* bp_ = (const f32x2*)b1s;                                    \
    PKADD(v1r[S][0], bp_[0]); PKADD(v1r[S][1], bp_[1]);                      \
    PKADD(v1r[S][2], bp_[2]); PKADD(v1r[S][3], bp_[3]);                      \
    PKADD(v1r[S][4], bp_[4]); PKADD(v1r[S][5], bp_[5]);                      \
    float m_ = fmaxf(fmaxf(fmaxf(v1r[S][0].x, v1r[S][0].y),                  \
                           fmaxf(v1r[S][1].x, v1r[S][1].y)),                 \
                     fmaxf(fmaxf(v1r[S][2].x, v1r[S][2].y),                  \
                           fmaxf(v1r[S][3].x, v1r[S][3].y)));                \
    m_ = fmaxf(m_, fmaxf(fmaxf(v1r[S][4].x, v1r[S][4].y),                    \
                         fmaxf(v1r[S][5].x, v1r[S][5].y)));                  \
    if (m_ >= th) {                                                          \
        _Pragma("unroll")                                                    \
        for (int jj = 0; jj < 6; ++jj) {                                     \
            _Pragma("unroll")                                                \
            for (int el = 0; el < 2; ++el) {                                 \
                const float v_ = el ? v1r[S][jj].y : v1r[S][jj].x;           \
                if (v_ >= th) {                                              \
                    if (el) v1r[S][jj].y = -__builtin_inff();                \
                    else    v1r[S][jj].x = -__builtin_inff();                \
                    const int c_ = jj * 2 + el;                              \
                    const int pyp_ = (Y) >> 1, pxp_ = (X) >> 1;              \
                    const int bidx_ = ((c_ * 144 + pyp_ * 12 + pxp_) << 2)   \
                                    | (((Y) & 1) << 1) | ((X) & 1);          \
                    f1b[bidx_] = (unsigned char)t;                           \
                }                                                            \
            }                                                                \
        }                                                                    \
    } } while (0)

// one phase-2 event: scalar-branched 3-way (no zero-row loads)
// per-accumulator FP order unchanged (one weight add per event per acc elem;
// dropping +0.0 adds can only flip -0<->+0, compare/add-neutral downstream)
#define P2_ONE(PA) do {                                                      \
    const int dA_ = (((PA) >> 4) & 15) - oyb_s;                              \
    if ((unsigned)dA_ < 6u) {                                                \
        const int ci_ = (PA) >> 8;                                           \
        const int px_ = (PA) & 15;                                           \
        const float* base_ = w2p + (px_ + 7) * 64 + lane;                    \
        if (dA_ == 0) {                                                      \
            const float* q0_ = base_ + (ci_ * 5) * 1216;                     \
            float lx_[8];                                                    \
            _Pragma("unroll")                                                \
            for (int j = 0; j < 8; ++j) lx_[j] = q0_[-(j * 64)];             \
            _Pragma("unroll")                                                \
            for (int j = 0; j < 8; ++j) v2r2[j].x += lx_[j];                 \
        } else if (dA_ == 5) {                                               \
            const float* q1_ = base_ + (ci_ * 5 + 4) * 1216;                 \
            float ly_[8];                                                    \
            _Pragma("unroll")                                                \
            for (int j = 0; j < 8; ++j) ly_[j] = q1_[-(j * 64)];             \
            _Pragma("unroll")                                                \
            for (int j = 0; j < 8; ++j) v2r2[j].y += ly_[j];                 \
        } else {                                                             \
            const float* q0_ = base_ + (ci_ * 5 + dA_) * 1216;               \
            const float* q1_ = q0_ - 1216;                                   \
            f32x2 la_[4];                                                    \
            _Pragma("unroll")                                                \
            for (int j = 0; j < 4; ++j) { la_[j].x = q0_[-(j * 64)]; la_[j].y = q1_[-(j * 64)]; } \
            _Pragma("unroll")                                                \
            for (int j = 0; j < 4; ++j) PKADD(v2r2[j], la_[j]);              \
            _Pragma("unroll")                                                \
            for (int j = 0; j < 4; ++j) { la_[j].x = q0_[-((4 + j) * 64)]; la_[j].y = q1_[-((4 + j) * 64)]; } \
            _Pragma("unroll")                                                \
            for (int j = 0; j < 4; ++j) PKADD(v2r2[4 + j], la_[j]);          \
        }                                                                    \
    } } while (0)

__device__ __forceinline__ unsigned min4b(unsigned w) {
    unsigned a = w & 255u, b = (w >> 8) & 255u, c = (w >> 16) & 255u, d = w >> 24;
    unsigned m0 = a < b ? a : b;
    unsigned m1 = c < d ? c : d;
    return m0 < m1 ? m0 : m1;
}

template <int USE_T>
__global__ void __launch_bounds__(256, 4)
snn_sim_kernel(const float* __restrict__ img,
               const float* __restrict__ w1g,
               const float* __restrict__ b1g,
               const float* __restrict__ b2g,
               const float* __restrict__ w2raw,
               const float* __restrict__ w2p,
               const float* __restrict__ fcw,
               const float* __restrict__ b3g,
               float* __restrict__ out) {
    const int bimg = blockIdx.x;
    const int tid  = threadIdx.x;
    const int lane = tid & 63;
    const int wv   = tid >> 6;   // 4 waves
    const int oyb_s = __builtin_amdgcn_readfirstlane(wv) * 2;   // wave-uniform SGPR
    const int wv_s  = oyb_s >> 1;

    __shared__ __align__(16) float w1s[300];   // transposed: [k=ky*5+kx][c]
    __shared__ __align__(8)  float b1s[12];
    __shared__ float th_lds[80];
    __shared__ unsigned char  stin[784];
    __shared__ __align__(8) unsigned short evlist[784];  // t-sorted input schedule
    __shared__ unsigned short off[81];         // input offsets; reused for e2 offsets
    __shared__ unsigned short o1[81];          // l1 event offsets
    __shared__ unsigned int   hist[80];
    __shared__ unsigned int   f1w[1728];       // l1 fire times: 4 constituent bytes / pooled loc
    __shared__ unsigned char  tmb1[1728];      // cached min4b per pooled loc
    __shared__ __align__(8) unsigned short ev1s[1728]; // sorted l1 events; reused as sorted e2
    __shared__ unsigned char  e2t[1024];       // l2 pooled fire time per NHWC flat idx

    unsigned char* f1b = (unsigned char*)f1w;

    // ---- init ----
    for (int i = tid; i < 300; i += 256) {
        int k = i / 12, c = i - k * 12;
        w1s[i] = w1g[c * 25 + k];
    }
    if (tid < 12) b1s[tid] = b1g[tid];
    if (tid < 80) {
        float xa = (0.0f - (float)tid) / 20.0f;
        th_lds[tid] = (float)exp((double)xa);            // correctly-rounded f32 exp
        hist[tid] = 0u;
    }
    for (int i = tid; i < 1728; i += 256) f1w[i] = 0xFFFFFFFFu;
    for (int i = tid; i < 1024; i += 256) e2t[i] = 0xFF;
    for (int i = tid; i < 784; i += 256) {
        float p = img[bimg * 784 + i];
        p = fmaxf(p, 1e-5f);
        float lg = (float)log((double)p);                // correctly-rounded f32 log
        float s = ceilf(fmaxf(-17.452274f * lg, 0.0f));
        stin[i] = (unsigned char)(int)fminf(s, 255.0f);
    }
    __syncthreads();
    for (int i = tid; i < 784; i += 256) {
        int t = stin[i];
        if (t < 80) atomicAdd(&hist[t], 1u);
    }
    __syncthreads();
    if (tid == 0) {
        unsigned int acc = 0;
        for (int t = 0; t < 80; ++t) { off[t] = (unsigned short)acc; acc += hist[t]; }
        off[80] = (unsigned short)acc;
    }
    __syncthreads();
    if (tid < 80) {                            // deterministic pixel-order fill per t-bin
        int k = off[tid];
        for (int i = 0; i < 784; ++i)
            if ((int)stin[i] == tid) {
                int py = i / 28;
                evlist[k++] = (unsigned short)((py << 8) | (i - py * 28));
            }
    }
    if (tid >= 80 && tid < 160) hist[tid - 80] = 0u;     // reset for l1 counting
    __syncthreads();

    // ================= PASS A: layer 1, all 80 steps, NO barriers =================
    {
        f32x2 v1r[3][6];
#pragma unroll
        for (int s = 0; s < 3; ++s)
#pragma unroll
            for (int j = 0; j < 6; ++j) v1r[s][j] = (f32x2){0.0f, 0.0f};

        const int y0 = tid / 24,  x0 = tid - y0 * 24;
        const int p1i = tid + 256;
        const int y1 = p1i / 24,  x1 = p1i - y1 * 24;
        const int has2 = (tid >= 192);         // 3rd slot on wave 3 (waves 0-1 do scans)
        const int p2i = tid + 320;             // 512..575 for tid 192..255
        const int y2 = p2i / 24,  x2 = p2i - y2 * 24;

        for (int t = 0; t < 80; ++t) {
            const float th = th_lds[t];
            const int e0 = off[t], e1t = off[t + 1];
            int e = e0;
            for (; e < e1t && (e & 3); ++e) { const unsigned a = evlist[e]; P1EVENT(a); }
            for (; e + 4 <= e1t; e += 4) {     // 4 events per ds_read_b64 (broadcast)
                const unsigned long long q = *(const unsigned long long*)&evlist[e];
                const unsigned a0 = (unsigned)(q & 0xFFFFu);
                const unsigned a1 = (unsigned)((q >> 16) & 0xFFFFu);
                const unsigned a2 = (unsigned)((q >> 32) & 0xFFFFu);
                const unsigned a3 = (unsigned)(q >> 48);
                P1EVENT(a0); P1EVENT(a1); P1EVENT(a2); P1EVENT(a3);
            }
            for (; e < e1t; ++e) { const unsigned a = evlist[e]; P1EVENT(a); }
            CHECK_V1F(0, y0, x0);
            CHECK_V1F(1, y1, x1);
            if (has2) CHECK_V1F(2, y2, x2);
        }
    }
    __syncthreads();                           // B1: f1 complete

    // ---- sort l1 pooled events by fire time (deterministic) ----
    for (int p = tid; p < 1728; p += 256) {
        unsigned tm = min4b(f1w[p]);
        tmb1[p] = (unsigned char)tm;           // cache for the fill scan
        if (tm < 80u) atomicAdd(&hist[tm], 1u);
    }
    __syncthreads();                           // B2
    if (tid == 0) {
        unsigned acc = 0;
        for (int t = 0; t < 80; ++t) { o1[t] = (unsigned short)acc; acc += hist[t]; }
        o1[80] = (unsigned short)acc;
    }
    __syncthreads();                           // B3
    if (tid < 80) {                            // deterministic p-order fill per t-bin
        int k = o1[tid];
        for (int p = 0; p < 1728; ++p) {
            if ((int)tmb1[p] == tid) {
                int c = p / 144;
                int rem = p - c * 144;
                int py = rem / 12;
                int px = rem - py * 12;
                ev1s[k++] = (unsigned short)((c << 8) | (py << 4) | px);
            }
        }
    }
    // reset for e2 counting — safe here: nothing reads hist until after B5
    if (tid >= 80 && tid < 160) hist[tid - 80] = 0u;
    __syncthreads();                           // B4: ev1s/o1 ready

    // ================= PASS B: layer 2, all 80 steps, NO barriers =================
    {
        f32x2 v2r2[8];                         // .x = row oyb, .y = row oyb+1, col j, co=lane
#pragma unroll
        for (int j = 0; j < 8; ++j) v2r2[j] = (f32x2){0.0f, 0.0f};
        const float b2v = b2g[lane];
        const f32x2 b2p = (f32x2){b2v, b2v};
        unsigned fired2 = 0u;                  // 4 pooled-l2 locs per thread, reg mask

        for (int t = 0; t < 80; ++t) {
            const float th = th_lds[t];
            const int e0 = o1[t], e1t = o1[t + 1];
            if (USE_T) {
                int e = e0;
                for (; e + 4 <= e1t; e += 4) {
                    const int p0 = __builtin_amdgcn_readfirstlane((int)ev1s[e]);
                    const int p1 = __builtin_amdgcn_readfirstlane((int)ev1s[e + 1]);
                    const int p2 = __builtin_amdgcn_readfirstlane((int)ev1s[e + 2]);
                    const int p3 = __builtin_amdgcn_readfirstlane((int)ev1s[e + 3]);
                    P2_ONE(p0); P2_ONE(p1); P2_ONE(p2); P2_ONE(p3);
                }
                for (; e < e1t; ++e) {
                    const int p0 = __builtin_amdgcn_readfirstlane((int)ev1s[e]);
                    P2_ONE(p0);
                }
            } else {
                for (int e = e0; e < e1t; ++e) {
                    const int pk = __builtin_amdgcn_readfirstlane((int)ev1s[e]);
                    const int dy0 = ((pk >> 4) & 15) - oyb_s;
                    if ((unsigned)dy0 >= 6u) continue;
                    const int ci = pk >> 8;
                    const int px = pk & 15;
                    const int dy1 = dy0 - 1;
                    const unsigned colm = ((0x1Fu << px) >> 4) & 0xFFu;
                    const unsigned m0 = ((unsigned)dy0 < 5u) ? colm : 0u;
                    const unsigned m1 = ((unsigned)dy1 < 5u) ? colm : 0u;
                    const int dy0c = dy0 < 0 ? 0 : (dy0 > 4 ? 4 : dy0);
                    const int dy1c = dy1 < 0 ? 0 : (dy1 > 4 ? 4 : dy1);
                    const float* cb = w2raw + lane * 300 + ci * 25;
                    const float* r0 = cb + dy0c * 5;
                    const float* r1 = cb + dy1c * 5;
#pragma unroll
                    for (int j = 0; j < 8; ++j) {
                        const int dx = px - j;
                        const int dxc = dx < 0 ? 0 : (dx > 4 ? 4 : dx);
                        v2r2[j].x = fmaf(r0[dxc], ((m0 >> j) & 1u) ? 1.0f : 0.0f, v2r2[j].x);
                        v2r2[j].y = fmaf(r1[dxc], ((m1 >> j) & 1u) ? 1.0f : 0.0f, v2r2[j].y);
                    }
                }
            }
            // layer2: stepwise bias pk-add + max-screen + rare exact pass
            PKADD(v2r2[0], b2p); PKADD(v2r2[1], b2p);
            PKADD(v2r2[2], b2p); PKADD(v2r2[3], b2p);
            PKADD(v2r2[4], b2p); PKADD(v2r2[5], b2p);
            PKADD(v2r2[6], b2p); PKADD(v2r2[7], b2p);
            float m2 = fmaxf(fmaxf(fmaxf(v2r2[0].x, v2r2[0].y), fmaxf(v2r2[1].x, v2r2[1].y)),
                             fmaxf(fmaxf(v2r2[2].x, v2r2[2].y), fmaxf(v2r2[3].x, v2r2[3].y)));
            m2 = fmaxf(m2, fmaxf(fmaxf(fmaxf(v2r2[4].x, v2r2[4].y), fmaxf(v2r2[5].x, v2r2[5].y)),
                                 fmaxf(fmaxf(v2r2[6].x, v2r2[6].y), fmaxf(v2r2[7].x, v2r2[7].y))));
            if (m2 >= th) {
#pragma unroll
                for (int j = 0; j < 8; ++j) {
#pragma unroll
                    for (int el = 0; el < 2; ++el) {
                        const float v = el ? v2r2[j].y : v2r2[j].x;
                        if (v >= th) {
                            if (el) v2r2[j].y = -__builtin_inff();
                            else    v2r2[j].x = -__builtin_inff();
                            const unsigned bit = 1u << (j >> 1);
                            if (!(fired2 & bit)) {
                                fired2 |= bit;
                                const int p2 = (wv_s * 4 + (j >> 1)) * 64 + lane;  // NHWC flat
                                e2t[p2] = (unsigned char)t;   // single write ever, race-free
                            }
                        }
                    }
                }
            }
        }
    }
    __syncthreads();                           // B5: e2t complete

    // ---- sort l2 events by fire time (deterministic) ----
    for (int p = tid; p < 1024; p += 256) {
        unsigned t = e2t[p];
        if (t < 80u) atomicAdd(&hist[t], 1u);
    }
    __syncthreads();                           // B6
    if (tid == 0) {
        unsigned acc = 0;
        for (int t = 0; t < 80; ++t) { off[t] = (unsigned short)acc; acc += hist[t]; }
        off[80] = (unsigned short)acc;
    }
    __syncthreads();                           // B7
    if (tid < 80) {                            // deterministic p2-order fill per t-bin
        int k = off[tid];
        for (int p = 0; p < 1024; ++p)
            if ((int)e2t[p] == tid) ev1s[k++] = (unsigned short)p;
    }
    __syncthreads();                           // B8

    // ---- output layer: replay t-sorted layer2 events (no feedback) ----
    if (tid < 10) {
        const float b3v = b3g[tid];
        float v = 0.0f;
        float ot = NOT_FIREDf;
        for (int t = 0; t < 80; ++t) {
            float acc = 0.0f;
            for (int e = off[t]; e < off[t + 1]; ++e)
                acc += fcw[(int)ev1s[e] * 10 + tid];
            v += acc + b3v;
            if (ot == NOT_FIREDf && v >= th_lds[t]) ot = (float)t;
        }
        out[bimg * 10 + tid] = ot;
    }
}

extern "C" void kernel_launch(void* const* d_in, const int* in_sizes, int n_in,
                              void* d_out, int out_size, void* d_ws, size_t ws_size,
                              hipStream_t stream) {
    const float* img = (const float*)d_in[0];
    const float* w1  = (const float*)d_in[1];
    const float* b1  = (const float*)d_in[2];
    const float* w2  = (const float*)d_in[3];
    const float* b2  = (const float*)d_in[4];
    const float* fcw = (const float*)d_in[5];
    const float* b3  = (const float*)d_in[6];
    float* out = (float*)d_out;

    const int B = in_sizes[0] / (28 * 28);

    float* w2p = (float*)d_ws;
    const int use_t = (ws_size >= 72960u * sizeof(float)) ? 1 : 0;
    if (use_t) {
        hipLaunchKernelGGL(w2_pad_kernel, dim3(285), dim3(256), 0, stream, w2, w2p);
        hipLaunchKernelGGL(snn_sim_kernel<1>, dim3(B), dim3(256), 0, stream,
                           img, w1, b1, b2, w2, w2p, fcw, b3, out);
    } else {
        hipLaunchKernelGGL(snn_sim_kernel<0>, dim3(B), dim3(256), 0, stream,
                           img, w1, b1, b2, w2, w2p, fcw, b3, out);
    }
}